// Round 4
// baseline (71.858 us; speedup 1.0000x reference)
//
#include <hip/hip_runtime.h>
#include <math.h>

#define NCOL 8192
#define NROW 4096
#define KSEL 819
#define TPB  256
#define VPT  8            // float4 per thread (32 elements/thread)
#define HSTRIDE 2048      // second histogram copy offset (ints)

// Per-column boost factors, recomputed every launch (deterministic).
__device__ __align__(16) float g_boost[NCOL];

__global__ void boost_kernel(const float* __restrict__ duty) {
    int i = blockIdx.x * blockDim.x + threadIdx.x;
    if (i < NCOL) {
        // target_density = 819/8192 exactly; boost_strength = 1
        float diff = (0.0999755859375f - duty[i]);
        g_boost[i] = (float)exp((double)diff);   // correctly-rounded f32 exp (matches np)
    }
}

__device__ __forceinline__ unsigned f2k(float f) {
    // monotone float -> uint map (total order)
    unsigned u = __float_as_uint(f);
    return u ^ (0x80000000u | (unsigned)((int)u >> 31));
}

__global__ __launch_bounds__(TPB) void kwinners_kernel(const float* __restrict__ x,
                                                       float* __restrict__ out) {
    // union: 2 histogram copies (2 x 2048 ints = 16 KB)  /  tie index list (8192 ushort)
    __shared__ __align__(16) unsigned char smem[16384];
    __shared__ int lds_wtot[4];
    __shared__ int lds_selarr[3], lds_Rarr[3];
    __shared__ int lds_E, lds_cnt;

    int* hist = (int*)smem;

    const int t = threadIdx.x;
    const int row = blockIdx.x;
    const int lane = t & 63;
    const int w = t >> 6;

    const float4* x4 = (const float4*)(x + (size_t)row * NCOL);
    const float4* b4 = (const float4*)g_boost;

    unsigned kr[VPT][4];

    // zero both histogram copies (16 ints per thread)
    {
        const int4 z = make_int4(0, 0, 0, 0);
        int4* h4 = (int4*)hist;
        h4[4 * t + 0] = z; h4[4 * t + 1] = z; h4[4 * t + 2] = z; h4[4 * t + 3] = z;
    }

    // load x + boost, compute sortable keys (keys live in registers)
#pragma unroll
    for (int j = 0; j < VPT; ++j) {
        const int v = t + TPB * j;
        float4 xx = x4[v];
        float4 bb = b4[v];
        kr[j][0] = f2k(xx.x * bb.x);
        kr[j][1] = f2k(xx.y * bb.y);
        kr[j][2] = f2k(xx.z * bb.z);
        kr[j][3] = f2k(xx.w * bb.w);
    }
    __syncthreads();

    // ---- 3-pass radix select, digits 11/11/10 bits (MSB->LSB) ----
    unsigned prefix = 0;
#pragma unroll
    for (int p = 0; p < 3; ++p) {
        const int sh  = (p == 0) ? 21 : (p == 1) ? 10 : 0;
        const int nb  = (p == 2) ? 1024 : 2048;
        const int bpt = nb / TPB;                 // 8, 8, 4 bins/thread
        int* myh = hist + ((lane >= 32) ? HSTRIDE : 0);

        // histogram (copy per 32-lane half-wave)
        if (p == 0) {
#pragma unroll
            for (int j = 0; j < VPT; ++j)
#pragma unroll
                for (int c = 0; c < 4; ++c)
                    atomicAdd(&myh[kr[j][c] >> 21], 1);
        } else {
            const int shp = (p == 1) ? 21 : 10;   // already-decided high bits
#pragma unroll
            for (int j = 0; j < VPT; ++j)
#pragma unroll
                for (int c = 0; c < 4; ++c) {
                    const unsigned key = kr[j][c];
                    if ((key >> shp) == (prefix >> shp))
                        atomicAdd(&myh[(key >> sh) & (nb - 1)], 1);
                }
        }
        __syncthreads();

        // scan part 1: read own bins (merge copies), zero them for next pass
        int arr[8];
        int ts = 0;
        {
            const int i4 = t * (bpt >> 2);        // first int4 chunk of my bins
            int4* h4a = (int4*)hist;
            int4* h4b = (int4*)(hist + HSTRIDE);
            const int4 z = make_int4(0, 0, 0, 0);
            int4 a0 = h4a[i4], b0 = h4b[i4];
            arr[0] = a0.x + b0.x; arr[1] = a0.y + b0.y;
            arr[2] = a0.z + b0.z; arr[3] = a0.w + b0.w;
            h4a[i4] = z; h4b[i4] = z;
            if (bpt == 8) {
                int4 a1 = h4a[i4 + 1], b1 = h4b[i4 + 1];
                arr[4] = a1.x + b1.x; arr[5] = a1.y + b1.y;
                arr[6] = a1.z + b1.z; arr[7] = a1.w + b1.w;
                h4a[i4 + 1] = z; h4b[i4 + 1] = z;
            }
#pragma unroll
            for (int b = 0; b < 8; ++b) if (b < bpt) ts += arr[b];
        }
        // wave-level inclusive suffix scan of thread sums
        int s = ts;
#pragma unroll
        for (int off = 1; off < 64; off <<= 1) {
            int o = __shfl_down(s, off);
            if (lane + off < 64) s += o;
        }
        if (lane == 0) lds_wtot[w] = s;
        __syncthreads();

        // scan part 2: the (unique) thread whose bin range crosses rank R selects
        int S_later = 0;
#pragma unroll
        for (int w2 = 0; w2 < 4; ++w2) if (w2 > w) S_later += lds_wtot[w2];
        const int S_above = (s - ts) + S_later;   // keys in bins above my top bin
        const int R0 = (p == 0) ? KSEL : lds_Rarr[p - 1];  // race-free: written last pass
        if (S_above < R0 && S_above + ts >= R0) {
            int cum = S_above;
            int selb = 0, selR = 0, selE = 0;
#pragma unroll
            for (int b = 7; b >= 0; --b) {
                if (b < bpt) {
                    const int nx = cum + arr[b];
                    if (cum < R0 && nx >= R0) { selb = t * bpt + b; selR = R0 - cum; selE = arr[b]; }
                    cum = nx;
                }
            }
            lds_selarr[p] = selb;
            lds_Rarr[p] = selR;
            if (p == 2) lds_E = selE;
        }
        __syncthreads();
        prefix |= ((unsigned)lds_selarr[p]) << sh;
    }

    const unsigned thresh = prefix;   // exact key of the K-th largest
    const int Rf = lds_Rarr[2];       // how many equal-to-thresh to keep
    const int E = lds_E;              // total equal-to-thresh
    unsigned dropm = 0;               // per-element demote bits (ties only)

    if (E > Rf) {                     // tie-break: keep lowest indices (lax.top_k)
        unsigned short* list = (unsigned short*)smem;   // capacity 8192 = NCOL, always safe
        if (t == 0) lds_cnt = 0;
        __syncthreads();
#pragma unroll
        for (int j = 0; j < VPT; ++j)
#pragma unroll
            for (int c = 0; c < 4; ++c) {
                if (kr[j][c] == thresh) {
                    int slot = atomicAdd(&lds_cnt, 1);
                    list[slot] = (unsigned short)(4 * (t + TPB * j) + c);
                }
            }
        __syncthreads();
        const int n = lds_cnt;
#pragma unroll
        for (int j = 0; j < VPT; ++j)
#pragma unroll
            for (int c = 0; c < 4; ++c) {
                if (kr[j][c] == thresh) {
                    const int col = 4 * (t + TPB * j) + c;
                    int rank = 0;
                    for (int i = 0; i < n; ++i) rank += (list[i] < col) ? 1 : 0;
                    if (rank >= Rf) dropm |= (1u << (4 * j + c));
                }
            }
    }

    // write: transmit ORIGINAL x at winners, 0 elsewhere (x re-read, L2/L3-hot)
    float4* o4 = (float4*)(out + (size_t)row * NCOL);
#pragma unroll
    for (int j = 0; j < VPT; ++j) {
        const int v = t + TPB * j;
        float4 xx = x4[v];
        float4 r;
        r.x = (kr[j][0] >= thresh && !((dropm >> (4 * j + 0)) & 1u)) ? xx.x : 0.0f;
        r.y = (kr[j][1] >= thresh && !((dropm >> (4 * j + 1)) & 1u)) ? xx.y : 0.0f;
        r.z = (kr[j][2] >= thresh && !((dropm >> (4 * j + 2)) & 1u)) ? xx.z : 0.0f;
        r.w = (kr[j][3] >= thresh && !((dropm >> (4 * j + 3)) & 1u)) ? xx.w : 0.0f;
        o4[v] = r;
    }
}

extern "C" void kernel_launch(void* const* d_in, const int* in_sizes, int n_in,
                              void* d_out, int out_size, void* d_ws, size_t ws_size,
                              hipStream_t stream) {
    const float* x = (const float*)d_in[0];        // [4096, 8192] f32
    const float* duty = (const float*)d_in[1];     // [8192] f32
    float* out = (float*)d_out;                    // [4096, 8192] f32
    (void)in_sizes; (void)n_in; (void)out_size; (void)d_ws; (void)ws_size;

    boost_kernel<<<(NCOL + TPB - 1) / TPB, TPB, 0, stream>>>(duty);
    kwinners_kernel<<<NROW, TPB, 0, stream>>>(x, out);
}

// Round 6
// 63.764 us; speedup vs baseline: 1.1269x; 1.1269x over previous
//
#include <hip/hip_runtime.h>
#include <math.h>

#define NCOL 8192
#define NROW 4096
#define KSEL 819
#define TPB  256
#define VPT  8            // f32x4 per thread (32 elements/thread)
#define LCAP 256          // candidate-list capacity (expected n ~ 1-3)
#define KPIV 0xBF866666u  // f2k(1.05f): survivor pivot in KEY space
#define NBKT 2048

typedef float f32x4 __attribute__((ext_vector_type(4)));

// Per-column boost factors, recomputed every launch (deterministic).
__device__ __align__(16) float g_boost[NCOL];

__global__ void boost_kernel(const float* __restrict__ duty) {
    int i = blockIdx.x * blockDim.x + threadIdx.x;
    if (i < NCOL) {
        // target_density = 819/8192 exactly; boost_strength = 1
        float diff = (0.0999755859375f - duty[i]);
        g_boost[i] = (float)exp((double)diff);   // correctly-rounded f32 exp (matches np)
    }
}

__device__ __forceinline__ unsigned f2k(float f) {
    // monotone float -> uint map (total order)
    unsigned u = __float_as_uint(f);
    return u ^ (0x80000000u | (unsigned)((int)u >> 31));
}

__device__ __forceinline__ int kbucket(unsigned k) {
    // pure-integer monotone bucket of the key; survivors (k>KPIV) -> [0, 2047]
    int b = (int)(k >> 13) - (int)(KPIV >> 13);
    return (b > NBKT - 1) ? (NBKT - 1) : b;
}

__global__ __launch_bounds__(TPB) void kwinners_kernel(const float* __restrict__ x,
                                                       float* __restrict__ out) {
    // smem: [0,8KB) 2048-bucket hist / fallback 256-bin hist / tie list (ushort, 16KB)
    //       [8KB,9KB) lkey[256]
    __shared__ __align__(16) unsigned char smem[16384];
    __shared__ int lds_wtot[4];
    __shared__ int lds_C, lds_cnt, lds_sel, lds_R1, lds_fE, lds_fR;
    __shared__ unsigned lds_th;

    int* hist = (int*)smem;
    unsigned* lkey = (unsigned*)(smem + 8192);

    const int t = threadIdx.x, row = blockIdx.x, lane = t & 63, w = t >> 6;
    const f32x4* x4 = (const f32x4*)(x + (size_t)row * NCOL);
    const f32x4* b4 = (const f32x4*)g_boost;

    unsigned kr[VPT][4];

    // zero bucket hist + scalars
    {
        int4* h4 = (int4*)hist;
        const int4 z = make_int4(0, 0, 0, 0);
        h4[2 * t] = z; h4[2 * t + 1] = z;
        if (t == 0) { lds_C = 0; lds_cnt = 0; lds_th = 0xFFFFFFFFu; }
    }

    // phase 1: load x + boost, keys -> registers (kept for all later phases)
#pragma unroll
    for (int j = 0; j < VPT; ++j) {
        f32x4 xx = x4[t + TPB * j];
        f32x4 bb = b4[t + TPB * j];
        kr[j][0] = f2k(xx.x * bb.x);
        kr[j][1] = f2k(xx.y * bb.y);
        kr[j][2] = f2k(xx.z * bb.z);
        kr[j][3] = f2k(xx.w * bb.w);
    }
    __syncthreads();

    // survivor count + sparse key-bucket histogram (survivors only)
    int cnt = 0;
#pragma unroll
    for (int j = 0; j < VPT; ++j)
#pragma unroll
        for (int c = 0; c < 4; ++c) {
            unsigned k = kr[j][c];
            if (k > KPIV) { ++cnt; atomicAdd(&hist[kbucket(k)], 1); }
        }
#pragma unroll
    for (int off = 32; off; off >>= 1) cnt += __shfl_down(cnt, off);
    if (lane == 0) atomicAdd(&lds_C, cnt);
    __syncthreads();
    const int C = lds_C;

    unsigned th = 0; int Rf = 0, E = 0; bool ok = false;

    if (C >= KSEL) {
        // one suffix-scan of 2048 buckets (8/thread) -> selected bucket + in-bucket rank
        int arr[8];
        {
            int4 a0 = ((const int4*)hist)[2 * t];
            int4 a1 = ((const int4*)hist)[2 * t + 1];
            arr[0] = a0.x; arr[1] = a0.y; arr[2] = a0.z; arr[3] = a0.w;
            arr[4] = a1.x; arr[5] = a1.y; arr[6] = a1.z; arr[7] = a1.w;
        }
        int ts = arr[0] + arr[1] + arr[2] + arr[3] + arr[4] + arr[5] + arr[6] + arr[7];
        int s = ts;
#pragma unroll
        for (int off = 1; off < 64; off <<= 1) {
            int o = __shfl_down(s, off);
            if (lane + off < 64) s += o;
        }
        if (lane == 0) lds_wtot[w] = s;
        __syncthreads();
        int S_later = 0;
#pragma unroll
        for (int w2 = 0; w2 < 4; ++w2) if (w2 > w) S_later += lds_wtot[w2];
        const int S_ab = (s - ts) + S_later;
        if (S_ab < KSEL && S_ab + ts >= KSEL) {
            int cum = S_ab, selb = 0, r1 = 0;
#pragma unroll
            for (int b = 7; b >= 0; --b) {
                int nx = cum + arr[b];
                if (cum < KSEL && nx >= KSEL) { selb = 8 * t + b; r1 = KSEL - cum; }
                cum = nx;
            }
            lds_sel = selb; lds_R1 = r1;
        }
        __syncthreads();
        const int sel = lds_sel, R1 = lds_R1;

        // gather the selected bucket's keys
#pragma unroll
        for (int j = 0; j < VPT; ++j)
#pragma unroll
            for (int c = 0; c < 4; ++c) {
                unsigned k = kr[j][c];
                if (kbucket(k) == sel) {
                    int sl = atomicAdd(&lds_cnt, 1);
                    if (sl < LCAP) lkey[sl] = k;
                }
            }
        __syncthreads();
        const int n = lds_cnt;
        if (n <= LCAP) {
            // propose th: exact R1-th largest of the tiny list
            if (t < n) {
                unsigned myk = lkey[t];
                int g = 0, e = 0;
                for (int i = 0; i < n; ++i) {
                    unsigned k2 = lkey[i];
                    g += (k2 > myk) ? 1 : 0;
                    e += (k2 == myk) ? 1 : 0;
                }
                if (g < R1 && g + e >= R1) lds_th = myk;
            }
            __syncthreads();
            th = lds_th;
            // CERTIFY globally: G=#{k>th}, E=#{k==th}; exact top-K predicate
            int ge = 0;
#pragma unroll
            for (int j = 0; j < VPT; ++j)
#pragma unroll
                for (int c = 0; c < 4; ++c) {
                    unsigned k = kr[j][c];
                    ge += (k > th ? 1 : 0) + (k == th ? (1 << 16) : 0);
                }
#pragma unroll
            for (int off = 32; off; off >>= 1) ge += __shfl_down(ge, off);
            if (lane == 0) lds_wtot[w] = ge;
            __syncthreads();
            const int GE = lds_wtot[0] + lds_wtot[1] + lds_wtot[2] + lds_wtot[3];
            const int G = GE & 0xFFFF, Eg = GE >> 16;
            if (G < KSEL && G + Eg >= KSEL) { ok = true; Rf = KSEL - G; E = Eg; }
        }
    }

    if (!ok) {
        // proven 4x8-bit key radix select (R1/R3/R4 structure) — guaranteed path
        unsigned prefix = 0; int R = KSEL;
        for (int p = 0; p < 4; ++p) {
            const int sh = 24 - 8 * p;
            hist[t] = 0;
            __syncthreads();
#pragma unroll
            for (int j = 0; j < VPT; ++j)
#pragma unroll
                for (int c = 0; c < 4; ++c) {
                    unsigned k = kr[j][c];
                    if (p == 0 || (k >> (sh + 8)) == (prefix >> (sh + 8)))
                        atomicAdd(&hist[(k >> sh) & 255u], 1);
                }
            __syncthreads();
            int h = hist[t], s2 = h;
#pragma unroll
            for (int off = 1; off < 64; off <<= 1) {
                int o = __shfl_down(s2, off);
                if (lane + off < 64) s2 += o;
            }
            if (lane == 0) lds_wtot[w] = s2;
            __syncthreads();
            int S_later = 0;
#pragma unroll
            for (int w2 = 0; w2 < 4; ++w2) if (w2 > w) S_later += lds_wtot[w2];
            const int S_ab = (s2 - h) + S_later;
            if (S_ab < R && S_ab + h >= R) { lds_sel = t; lds_fR = R - S_ab; lds_fE = h; }
            __syncthreads();
            prefix |= ((unsigned)lds_sel) << sh;
            R = lds_fR;
        }
        th = prefix; Rf = R; E = lds_fE;
    }

    // tie-break (lax.top_k keeps lowest indices) — rare
    unsigned dropm = 0;
    if (E > Rf) {
        unsigned short* tl = (unsigned short*)smem;   // cap 8192 = NCOL, always safe
        __syncthreads();
        if (t == 0) lds_cnt = 0;
        __syncthreads();
#pragma unroll
        for (int j = 0; j < VPT; ++j)
#pragma unroll
            for (int c = 0; c < 4; ++c)
                if (kr[j][c] == th) {
                    int sl = atomicAdd(&lds_cnt, 1);
                    tl[sl] = (unsigned short)(4 * (t + TPB * j) + c);
                }
        __syncthreads();
        const int ntie = lds_cnt;
#pragma unroll
        for (int j = 0; j < VPT; ++j)
#pragma unroll
            for (int c = 0; c < 4; ++c)
                if (kr[j][c] == th) {
                    const int col = 4 * (t + TPB * j) + c;
                    int rank = 0;
                    for (int i = 0; i < ntie; ++i) rank += (tl[i] < col) ? 1 : 0;
                    if (rank >= Rf) dropm |= (1u << (4 * j + c));
                }
    }

    // write: transmit ORIGINAL x at winners, 0 elsewhere (x re-read, cache-hot)
    f32x4* o4 = (f32x4*)(out + (size_t)row * NCOL);
#pragma unroll
    for (int j = 0; j < VPT; ++j) {
        f32x4 xx = x4[t + TPB * j];
        f32x4 r;
        r.x = (kr[j][0] >= th && !((dropm >> (4 * j + 0)) & 1u)) ? xx.x : 0.0f;
        r.y = (kr[j][1] >= th && !((dropm >> (4 * j + 1)) & 1u)) ? xx.y : 0.0f;
        r.z = (kr[j][2] >= th && !((dropm >> (4 * j + 2)) & 1u)) ? xx.z : 0.0f;
        r.w = (kr[j][3] >= th && !((dropm >> (4 * j + 3)) & 1u)) ? xx.w : 0.0f;
        __builtin_nontemporal_store(r, &o4[t + TPB * j]);
    }
}

extern "C" void kernel_launch(void* const* d_in, const int* in_sizes, int n_in,
                              void* d_out, int out_size, void* d_ws, size_t ws_size,
                              hipStream_t stream) {
    const float* x = (const float*)d_in[0];        // [4096, 8192] f32
    const float* duty = (const float*)d_in[1];     // [8192] f32
    float* out = (float*)d_out;                    // [4096, 8192] f32
    (void)in_sizes; (void)n_in; (void)out_size; (void)d_ws; (void)ws_size;

    boost_kernel<<<(NCOL + TPB - 1) / TPB, TPB, 0, stream>>>(duty);
    kwinners_kernel<<<NROW, TPB, 0, stream>>>(x, out);
}